// Round 9
// baseline (161.772 us; speedup 1.0000x reference)
//
#include <hip/hip_runtime.h>
#include <hip/hip_bf16.h>

// Problem constants (fixed by setup_inputs)
#define NSAMP 16384   // N
#define BB    4       // batch
#define C2D   128
#define C3D   128
#define HH    96
#define WW    160
#define COUT  128
#define KK    256     // fan_in
#define HW    (HH*WW) // 15360
#define TN    64      // samples per fuse block
#define CATS  264     // cat row stride bf16: word stride 132 == 4 (mod 32);
                      // b128 frag reads and uint2 blend writes both hit the
                      // per-access minimum pass count (conflict-free)
#define TS    136     // transpose LDS row stride shorts: word stride 68

typedef __attribute__((ext_vector_type(8))) short bf16x8;  // 8 bf16 = 4 VGPRs (MFMA A/B frag)
typedef __attribute__((ext_vector_type(4))) float f32x4;   // MFMA C/D frag

__device__ __forceinline__ float bf16lo(unsigned int u) { return __uint_as_float(u << 16); }
__device__ __forceinline__ float bf16hi(unsigned int u) { return __uint_as_float(u & 0xffff0000u); }
__device__ __forceinline__ unsigned int pack2(float a, float b) {
    union { __hip_bfloat162 h; unsigned int u; } c;
    c.h = __float22bfloat162_rn(make_float2(a, b));   // RNE, x in low 16 bits
    return c.u;
}

// ---------------------------------------------------------------------------
// Kernel 1: f2d fp32 [B,C2D,H,W] -> f2dt bf16 channel-last [B,HW,C2D],
// PLUS (blocks 480..495) W fp32 [COUT,KK] -> Wb bf16 row-major (merged to
// save one launch gap). Transpose tile = 128 hw x 128 c, 512 threads,
// 480 blocks (XCD-swizzled). Verified correct in rounds 4-7.
// LDS word layout: word(row, w) = row*68 + (w ^ xk(row)), xk = 4*((row>>3)&7).
// Bank check (corrected r8->r9): stage b32 bank = (4*lane + w) mod 32; the 8
// lanes sharing 4*lane mod 32 carry 8 distinct XOR keys in bank bits 2-4 ->
// 8 distinct banks; wave total 2 lanes/bank = free. Readout b128 16B-aligned,
// conflict-free.
// ---------------------------------------------------------------------------
__global__ __launch_bounds__(512) void transpose_cvt_kernel(
    const float* __restrict__ f2d, unsigned short* __restrict__ f2dt,
    const float* __restrict__ Wm,  unsigned short* __restrict__ Wb)
{
    __shared__ unsigned short t[128 * TS];   // 34816 B
    const int raw = blockIdx.x;
    if (raw >= 480) {                        // merged wcvt tail blocks
        const int i = (raw - 480) * 512 + threadIdx.x;   // 8192 float4 total
        const float4 v = ((const float4*)Wm)[i];
        uint2 o;
        o.x = pack2(v.x, v.y);
        o.y = pack2(v.z, v.w);
        ((uint2*)Wb)[i] = o;
        return;
    }
    unsigned int* tw = (unsigned int*)t;
    const int tid  = threadIdx.x;
    const int lane = tid & 63;
    const int wv   = tid >> 6;               // 0..7: channels [16wv, 16wv+16)
    const int blk  = (raw & 7) * 60 + (raw >> 3);   // 480 % 8 == 0, bijective
    const int b    = blk / 120;
    const int hw0  = (blk % 120) * 128;

    const int xk = 4 * ((lane >> 3) & 7);    // row-XOR key (rows lane, lane+64 share it)
    const float* src = f2d + (size_t)b * C2D * HW + hw0 + lane;
    #pragma unroll
    for (int st = 0; st < 8; ++st) {
        const int c = wv * 16 + st * 2;
        const float va0 = src[(size_t)c * HW];
        const float vb0 = src[(size_t)(c + 1) * HW];
        const float va1 = src[(size_t)c * HW + 64];
        const float vb1 = src[(size_t)(c + 1) * HW + 64];
        const int w = (c >> 1) ^ xk;
        tw[lane        * (TS / 2) + w] = pack2(va0, vb0);
        tw[(lane + 64) * (TS / 2) + w] = pack2(va1, vb1);
    }
    __syncthreads();
    #pragma unroll
    for (int it = 0; it < 4; ++it) {
        const int r  = it * 32 + (tid >> 4);
        const int rk = 4 * ((r >> 3) & 7);
        const uint4 v = *(const uint4*)&tw[r * (TS / 2) + (((tid & 15) * 4) ^ rk)];
        *(uint4*)&f2dt[((size_t)b * HW + hw0 + r) * C2D + (tid & 15) * 8] = v;
    }
}

// ---------------------------------------------------------------------------
// Kernel 2 helper: blend 4 gathered corner fragments (4 channels each) and
// write the packed bf16 result into the cat LDS row. (Function, not macro:
// a macro parameter named `w` would collide with float4's `.w` member.)
// Write pattern: uint2 per lane, 128 words/wave over 32 banks = 4 passes,
// distribution exactly 4 words/bank -> minimum (conflict-free).
// ---------------------------------------------------------------------------
__device__ __forceinline__ void blend_write(
    const uint2* cv, const float4 bw, unsigned int* catw, int row, int ch4)
{
    float r0 = bw.x * bf16lo(cv[0].x) + bw.y * bf16lo(cv[1].x)
             + bw.z * bf16lo(cv[2].x) + bw.w * bf16lo(cv[3].x);
    float r1 = bw.x * bf16hi(cv[0].x) + bw.y * bf16hi(cv[1].x)
             + bw.z * bf16hi(cv[2].x) + bw.w * bf16hi(cv[3].x);
    float r2 = bw.x * bf16lo(cv[0].y) + bw.y * bf16lo(cv[1].y)
             + bw.z * bf16lo(cv[2].y) + bw.w * bf16lo(cv[3].y);
    float r3 = bw.x * bf16hi(cv[0].y) + bw.y * bf16hi(cv[1].y)
             + bw.z * bf16hi(cv[2].y) + bw.w * bf16hi(cv[3].y);
    uint2 pk;
    pk.x = pack2(r0, r1);
    pk.y = pack2(r2, r3);
    *(uint2*)&catw[row * (CATS / 2) + (ch4 >> 1)] = pk;
}

// ---------------------------------------------------------------------------
// Kernel 2: fused bilinear-gather + concat + bf16 MFMA GEMM + bias + leaky.
// 256 threads (4 waves), TN=64, grid 1024 XCD-swizzled, 4 blocks/CU.
// Single-barrier structure (round 6, verified 126.2 us):
//   params (registers) -> issue gather A -> f3d load+pack (covers A) ->
//   issue gather B -> blend A (covers B) -> A-FRAG PREFETCH (new, r9) ->
//   blend B (covers A-frag flight) -> ONE barrier -> GEMM (LDS-only reads)
//   -> bias + leaky epilogue.
// Register budget at the prefetch point: gb(32) + afrag(64) + ~20 misc = 116
// < 128 cap; GEMM phase: afrag(64) + acc(32) + temps ~ 114. No spill.
// launch_bounds (256,4): VGPR cap 128.
// ---------------------------------------------------------------------------
__global__ __launch_bounds__(256, 4) void fuse_kernel(
    const float*          __restrict__ xy,     // [B,2,N]
    const unsigned short* __restrict__ f2dt,   // [B,HW,C2D] bf16
    const float*          __restrict__ f3d,    // [B,C3D,N]
    const unsigned short* __restrict__ Wb,     // [COUT,KK] bf16
    const float*          __restrict__ bias,   // [COUT]
    float* __restrict__ out)                   // [B,COUT,N]
{
    __shared__ unsigned short cat[TN * CATS];  // 33792 B (only LDS)
    unsigned int* catw = (unsigned int*)cat;

    const int tid  = threadIdx.x;
    const int lane = tid & 63;
    const int wv   = tid >> 6;                 // 0..3
    // XCD-bijective swizzle (1024 % 8 == 0): one XCD's blocks stay in one
    // batch -> f2dt slice (3.93 MB) resident in that XCD's 4-MB L2.
    const int blk  = (blockIdx.x & 7) * 128 + (blockIdx.x >> 3);
    const int b    = blk >> 8;                 // 256 tiles per batch
    const int n0   = (blk & 255) * TN;

    // ---- bilinear params in registers: lane holds sample wv*16 + (lane&15).
    // 4x redundant across quads; xy loads are 64B runs, L1-broadcast. ----
    float w4x, w4y, w4z, w4w;
    int   o4x, o4y, o4z, o4w;
    {
        const int n = n0 + wv * 16 + (lane & 15);
        float x = xy[((size_t)b * 2 + 0) * NSAMP + n];
        float y = xy[((size_t)b * 2 + 1) * NSAMP + n];
        float xf = floorf(x), yf = floorf(y);
        float wx1 = x - xf, wy1 = y - yf;
        float wx0 = 1.0f - wx1, wy0 = 1.0f - wy1;
        int x0 = (int)xf, y0 = (int)yf;
        int x1 = x0 + 1, y1 = y0 + 1;
        if (x0 < 0 || x0 > WW - 1) wx0 = 0.0f;
        if (x1 < 0 || x1 > WW - 1) wx1 = 0.0f;
        if (y0 < 0 || y0 > HH - 1) wy0 = 0.0f;
        if (y1 < 0 || y1 > HH - 1) wy1 = 0.0f;
        x0 = min(max(x0, 0), WW - 1);
        x1 = min(max(x1, 0), WW - 1);
        y0 = min(max(y0, 0), HH - 1);
        y1 = min(max(y1, 0), HH - 1);
        w4x = wx0 * wy0; w4y = wx1 * wy0; w4z = wx0 * wy1; w4w = wx1 * wy1;
        o4x = y0 * WW + x0; o4y = y0 * WW + x1;
        o4z = y1 * WW + x0; o4w = y1 * WW + x1;
    }

    const int s2  = lane >> 5;                 // half-wave id
    const int ch4 = (lane & 31) * 4;           // 4 channels per lane
    const unsigned short* fb = f2dt + (size_t)b * HW * C2D + ch4;

    // ---- issue gather batch A: half-wave s2 covers samples wv*16 + i*2+s2,
    // uint2 = 4 channels/lane, each corner row a 256-B coalesced run ----
    uint2 ga[4][4];
    #pragma unroll
    for (int i = 0; i < 4; ++i) {
        const int jl = i * 2 + s2;             // 0..7
        int4 o;
        o.x = __shfl(o4x, jl); o.y = __shfl(o4y, jl);
        o.z = __shfl(o4z, jl); o.w = __shfl(o4w, jl);
        ga[i][0] = *(const uint2*)(fb + (size_t)o.x * C2D);
        ga[i][1] = *(const uint2*)(fb + (size_t)o.y * C2D);
        ga[i][2] = *(const uint2*)(fb + (size_t)o.z * C2D);
        ga[i][3] = *(const uint2*)(fb + (size_t)o.w * C2D);
    }

    // ---- f3d -> cat[n][128+c] (covers batch-A flight). lane = sample,
    // wave wv covers 32 channels; coalesced 4B loads, b128 LDS writes. ----
    {
        const float* p3 = f3d + (size_t)(b * C3D) * NSAMP + n0 + lane;
        #pragma unroll
        for (int ch = 0; ch < 4; ++ch) {
            const int cbase = wv * 32 + ch * 8;
            float v[8];
            #pragma unroll
            for (int t = 0; t < 8; ++t) v[t] = p3[(size_t)(cbase + t) * NSAMP];
            uint4 pk;
            pk.x = pack2(v[0], v[1]);
            pk.y = pack2(v[2], v[3]);
            pk.z = pack2(v[4], v[5]);
            pk.w = pack2(v[6], v[7]);
            *(uint4*)&catw[lane * (CATS / 2) + (C2D / 2) + (cbase >> 1)] = pk;
        }
    }

    // ---- issue gather batch B: samples wv*16 + 8 + i*2+s2 ----
    uint2 gb[4][4];
    #pragma unroll
    for (int i = 0; i < 4; ++i) {
        const int jl = 8 + i * 2 + s2;         // 8..15
        int4 o;
        o.x = __shfl(o4x, jl); o.y = __shfl(o4y, jl);
        o.z = __shfl(o4z, jl); o.w = __shfl(o4w, jl);
        gb[i][0] = *(const uint2*)(fb + (size_t)o.x * C2D);
        gb[i][1] = *(const uint2*)(fb + (size_t)o.y * C2D);
        gb[i][2] = *(const uint2*)(fb + (size_t)o.z * C2D);
        gb[i][3] = *(const uint2*)(fb + (size_t)o.w * C2D);
    }

    // ---- blend A (VALU, covers batch-B flight) ----
    #pragma unroll
    for (int i = 0; i < 4; ++i) {
        const int jl = i * 2 + s2;
        float4 bw;
        bw.x = __shfl(w4x, jl); bw.y = __shfl(w4y, jl);
        bw.z = __shfl(w4z, jl); bw.w = __shfl(w4w, jl);
        blend_write(ga[i], bw, catw, wv * 16 + jl, ch4);
    }

    // ---- A-fragment prefetch (r9): Wb rows are barrier-independent and
    // L2-hot; issue all 16 b128 loads now so their ~200-cyc latency hides
    // under blend-B's VALU instead of stalling the first MFMAs. ----
    const int quad = lane >> 4;
    const int nloc = lane & 15;
    const unsigned short* wb0 = Wb + (size_t)(wv * 32 + nloc) * KK + quad * 8;
    bf16x8 afrag[8][2];
    #pragma unroll
    for (int ks = 0; ks < 8; ++ks) {
        afrag[ks][0] = *(const bf16x8*)(wb0 + ks * 32);
        afrag[ks][1] = *(const bf16x8*)(wb0 + 16 * KK + ks * 32);
    }

    // ---- blend B ----
    #pragma unroll
    for (int i = 0; i < 4; ++i) {
        const int jl = 8 + i * 2 + s2;
        float4 bw;
        bw.x = __shfl(w4x, jl); bw.y = __shfl(w4y, jl);
        bw.z = __shfl(w4z, jl); bw.w = __shfl(w4w, jl);
        blend_write(gb[i], bw, catw, wv * 16 + jl, ch4);
    }
    __syncthreads();   // the ONLY barrier: full cat tile ready

    // ---- GEMM: D[128 x 64] = Wb[128 x 256] @ cat^T, 32 MFMA, LDS-only ----
    f32x4 acc[2][4];
    #pragma unroll
    for (int mt = 0; mt < 2; ++mt)
        #pragma unroll
        for (int nt = 0; nt < 4; ++nt)
            acc[mt][nt] = (f32x4){0.f, 0.f, 0.f, 0.f};

    #pragma unroll 2
    for (int ks = 0; ks < 8; ++ks) {
        const int k0 = ks * 32;
        #pragma unroll
        for (int nt = 0; nt < 4; ++nt) {
            const bf16x8 bfrag = *(const bf16x8*)
                &cat[(nt * 16 + nloc) * CATS + k0 + quad * 8];
            acc[0][nt] = __builtin_amdgcn_mfma_f32_16x16x32_bf16(
                afrag[ks][0], bfrag, acc[0][nt], 0, 0, 0);
            acc[1][nt] = __builtin_amdgcn_mfma_f32_16x16x32_bf16(
                afrag[ks][1], bfrag, acc[1][nt], 0, 0, 0);
        }
    }

    // ---- Epilogue: bias + leaky-relu; C/D layout col=lane&15, row=quad*4+r ----
    #pragma unroll
    for (int mt = 0; mt < 2; ++mt) {
        const int cobase = wv * 32 + mt * 16 + quad * 4;
        float bv[4];
        #pragma unroll
        for (int r = 0; r < 4; ++r) bv[r] = bias[cobase + r];
        #pragma unroll
        for (int nt = 0; nt < 4; ++nt) {
            float* po = out + (size_t)(b * COUT + cobase) * NSAMP
                      + n0 + nt * 16 + nloc;
            #pragma unroll
            for (int r = 0; r < 4; ++r) {
                float yv = acc[mt][nt][r] + bv[r];
                yv = (yv >= 0.0f) ? yv : 0.1f * yv;
                po[(size_t)r * NSAMP] = yv;
            }
        }
    }
}

extern "C" void kernel_launch(void* const* d_in, const int* in_sizes, int n_in,
                              void* d_out, int out_size, void* d_ws, size_t ws_size,
                              hipStream_t stream) {
    const float* xy   = (const float*)d_in[0];
    const float* f2d  = (const float*)d_in[1];
    const float* f3d  = (const float*)d_in[2];
    const float* Wm   = (const float*)d_in[3];
    const float* bias = (const float*)d_in[4];
    float* out = (float*)d_out;

    // ws layout: f2dt bf16 [B*HW*C2D] (15.73 MB), then Wb bf16 [COUT*KK]
    unsigned short* f2dt = (unsigned short*)d_ws;
    unsigned short* Wb   = f2dt + (size_t)BB * HW * C2D;

    // 480 transpose blocks + 16 wcvt blocks in one launch
    transpose_cvt_kernel<<<dim3(496), 512, 0, stream>>>(f2d, f2dt, Wm, Wb);
    fuse_kernel<<<dim3(BB * (NSAMP / TN)), 256, 0, stream>>>(
        xy, f2dt, f3d, Wb, bias, out);
}

// Round 10
// 125.266 us; speedup vs baseline: 1.2914x; 1.2914x over previous
//
#include <hip/hip_runtime.h>
#include <hip/hip_bf16.h>

// Problem constants (fixed by setup_inputs)
#define NSAMP 16384   // N
#define BB    4       // batch
#define C2D   128
#define C3D   128
#define HH    96
#define WW    160
#define COUT  128
#define KK    256     // fan_in
#define HW    (HH*WW) // 15360
#define TN    64      // samples per fuse block
#define CATS  264     // cat row stride bf16: word stride 132 == 4 (mod 32);
                      // b128 frag reads and uint2 blend writes both hit the
                      // per-access minimum pass count (conflict-free)
#define TS    136     // transpose LDS row stride shorts: word stride 68

typedef __attribute__((ext_vector_type(8))) short bf16x8;  // 8 bf16 = 4 VGPRs (MFMA A/B frag)
typedef __attribute__((ext_vector_type(4))) float f32x4;   // MFMA C/D frag

__device__ __forceinline__ float bf16lo(unsigned int u) { return __uint_as_float(u << 16); }
__device__ __forceinline__ float bf16hi(unsigned int u) { return __uint_as_float(u & 0xffff0000u); }
__device__ __forceinline__ unsigned int pack2(float a, float b) {
    union { __hip_bfloat162 h; unsigned int u; } c;
    c.h = __float22bfloat162_rn(make_float2(a, b));   // RNE, x in low 16 bits
    return c.u;
}

// ---------------------------------------------------------------------------
// Kernel 1: f2d fp32 [B,C2D,H,W] -> f2dt bf16 channel-last [B,HW,C2D],
// PLUS (blocks 480..495) W fp32 [COUT,KK] -> Wb bf16 row-major (merged to
// save one launch gap). Transpose tile = 128 hw x 128 c, 512 threads,
// 480 blocks (XCD-swizzled). Verified correct rounds 4-7 (round-6 = 126.2us).
// LDS word layout: word(row, w) = row*68 + (w ^ xk(row)), xk = 4*((row>>3)&7).
// Stage b32 bank = (4*lane + w) mod 32; the 8 lanes sharing 4*lane mod 32
// carry 8 distinct XOR keys in bank bits 2-4 -> 8 distinct banks -> 2
// lanes/bank total (free). Readout b128 16B-aligned, conflict-free.
// ---------------------------------------------------------------------------
__global__ __launch_bounds__(512) void transpose_cvt_kernel(
    const float* __restrict__ f2d, unsigned short* __restrict__ f2dt,
    const float* __restrict__ Wm,  unsigned short* __restrict__ Wb)
{
    __shared__ unsigned short t[128 * TS];   // 34816 B
    const int raw = blockIdx.x;
    if (raw >= 480) {                        // merged wcvt tail blocks
        const int i = (raw - 480) * 512 + threadIdx.x;   // 8192 float4 total
        const float4 v = ((const float4*)Wm)[i];
        uint2 o;
        o.x = pack2(v.x, v.y);
        o.y = pack2(v.z, v.w);
        ((uint2*)Wb)[i] = o;
        return;
    }
    unsigned int* tw = (unsigned int*)t;
    const int tid  = threadIdx.x;
    const int lane = tid & 63;
    const int wv   = tid >> 6;               // 0..7: channels [16wv, 16wv+16)
    const int blk  = (raw & 7) * 60 + (raw >> 3);   // 480 % 8 == 0, bijective
    const int b    = blk / 120;
    const int hw0  = (blk % 120) * 128;

    const int xk = 4 * ((lane >> 3) & 7);    // row-XOR key (rows lane, lane+64 share it)
    const float* src = f2d + (size_t)b * C2D * HW + hw0 + lane;
    #pragma unroll
    for (int st = 0; st < 8; ++st) {
        const int c = wv * 16 + st * 2;
        const float va0 = src[(size_t)c * HW];
        const float vb0 = src[(size_t)(c + 1) * HW];
        const float va1 = src[(size_t)c * HW + 64];
        const float vb1 = src[(size_t)(c + 1) * HW + 64];
        const int w = (c >> 1) ^ xk;
        tw[lane        * (TS / 2) + w] = pack2(va0, vb0);
        tw[(lane + 64) * (TS / 2) + w] = pack2(va1, vb1);
    }
    __syncthreads();
    #pragma unroll
    for (int it = 0; it < 4; ++it) {
        const int r  = it * 32 + (tid >> 4);
        const int rk = 4 * ((r >> 3) & 7);
        const uint4 v = *(const uint4*)&tw[r * (TS / 2) + (((tid & 15) * 4) ^ rk)];
        *(uint4*)&f2dt[((size_t)b * HW + hw0 + r) * C2D + (tid & 15) * 8] = v;
    }
}

// ---------------------------------------------------------------------------
// Kernel 2 helper: blend 4 gathered corner fragments (4 channels each) and
// write the packed bf16 result into the cat LDS row. (Function, not macro:
// a macro parameter named `w` would collide with float4's `.w` member.)
// Write pattern: uint2 per lane, 128 words/wave over 32 banks = 4 passes,
// distribution exactly 4 words/bank -> minimum (conflict-free).
// ---------------------------------------------------------------------------
__device__ __forceinline__ void blend_write(
    const uint2* cv, const float4 bw, unsigned int* catw, int row, int ch4)
{
    float r0 = bw.x * bf16lo(cv[0].x) + bw.y * bf16lo(cv[1].x)
             + bw.z * bf16lo(cv[2].x) + bw.w * bf16lo(cv[3].x);
    float r1 = bw.x * bf16hi(cv[0].x) + bw.y * bf16hi(cv[1].x)
             + bw.z * bf16hi(cv[2].x) + bw.w * bf16hi(cv[3].x);
    float r2 = bw.x * bf16lo(cv[0].y) + bw.y * bf16lo(cv[1].y)
             + bw.z * bf16lo(cv[2].y) + bw.w * bf16lo(cv[3].y);
    float r3 = bw.x * bf16hi(cv[0].y) + bw.y * bf16hi(cv[1].y)
             + bw.z * bf16hi(cv[2].y) + bw.w * bf16hi(cv[3].y);
    uint2 pk;
    pk.x = pack2(r0, r1);
    pk.y = pack2(r2, r3);
    *(uint2*)&catw[row * (CATS / 2) + (ch4 >> 1)] = pk;
}

// ---------------------------------------------------------------------------
// Kernel 2: fused bilinear-gather + concat + bf16 MFMA GEMM + bias + leaky.
// EXACT round-6 structure (verified 126.2 us) + s_setprio around the MFMA
// cluster (T5: fuse blocks are independent at 4/CU -> phase-diverse regime
// where setprio measured +4-7%).
// NOTE (round-9 lesson, rule #20): NO register array for A-frags — a runtime-
// indexed ext_vector array (afrag[ks] under partial unroll) goes to scratch:
// VGPR collapsed to 64, +70 MB spill traffic, fuse 28 -> 64 us. A-frags are
// loaded via pointer arithmetic inside the loop instead.
// 256 threads (4 waves), TN=64, grid 1024 XCD-swizzled, 4 blocks/CU.
//   params (registers) -> issue gather A -> f3d load+pack (covers A) ->
//   issue gather B -> blend A (covers B) -> blend B -> ONE barrier ->
//   GEMM (K=256, 32 MFMA) -> bias + leaky epilogue.
// launch_bounds (256,4): VGPR cap 128.
// ---------------------------------------------------------------------------
__global__ __launch_bounds__(256, 4) void fuse_kernel(
    const float*          __restrict__ xy,     // [B,2,N]
    const unsigned short* __restrict__ f2dt,   // [B,HW,C2D] bf16
    const float*          __restrict__ f3d,    // [B,C3D,N]
    const unsigned short* __restrict__ Wb,     // [COUT,KK] bf16
    const float*          __restrict__ bias,   // [COUT]
    float* __restrict__ out)                   // [B,COUT,N]
{
    __shared__ unsigned short cat[TN * CATS];  // 33792 B (only LDS)
    unsigned int* catw = (unsigned int*)cat;

    const int tid  = threadIdx.x;
    const int lane = tid & 63;
    const int wv   = tid >> 6;                 // 0..3
    // XCD-bijective swizzle (1024 % 8 == 0): one XCD's blocks stay in one
    // batch -> f2dt slice (3.93 MB) resident in that XCD's 4-MB L2.
    const int blk  = (blockIdx.x & 7) * 128 + (blockIdx.x >> 3);
    const int b    = blk >> 8;                 // 256 tiles per batch
    const int n0   = (blk & 255) * TN;

    // ---- bilinear params in registers: lane holds sample wv*16 + (lane&15).
    // 4x redundant across quads; xy loads are 64B runs, L1-broadcast. ----
    float w4x, w4y, w4z, w4w;
    int   o4x, o4y, o4z, o4w;
    {
        const int n = n0 + wv * 16 + (lane & 15);
        float x = xy[((size_t)b * 2 + 0) * NSAMP + n];
        float y = xy[((size_t)b * 2 + 1) * NSAMP + n];
        float xf = floorf(x), yf = floorf(y);
        float wx1 = x - xf, wy1 = y - yf;
        float wx0 = 1.0f - wx1, wy0 = 1.0f - wy1;
        int x0 = (int)xf, y0 = (int)yf;
        int x1 = x0 + 1, y1 = y0 + 1;
        if (x0 < 0 || x0 > WW - 1) wx0 = 0.0f;
        if (x1 < 0 || x1 > WW - 1) wx1 = 0.0f;
        if (y0 < 0 || y0 > HH - 1) wy0 = 0.0f;
        if (y1 < 0 || y1 > HH - 1) wy1 = 0.0f;
        x0 = min(max(x0, 0), WW - 1);
        x1 = min(max(x1, 0), WW - 1);
        y0 = min(max(y0, 0), HH - 1);
        y1 = min(max(y1, 0), HH - 1);
        w4x = wx0 * wy0; w4y = wx1 * wy0; w4z = wx0 * wy1; w4w = wx1 * wy1;
        o4x = y0 * WW + x0; o4y = y0 * WW + x1;
        o4z = y1 * WW + x0; o4w = y1 * WW + x1;
    }

    const int s2  = lane >> 5;                 // half-wave id
    const int ch4 = (lane & 31) * 4;           // 4 channels per lane
    const unsigned short* fb = f2dt + (size_t)b * HW * C2D + ch4;

    // ---- issue gather batch A: half-wave s2 covers samples wv*16 + i*2+s2,
    // uint2 = 4 channels/lane, each corner row a 256-B coalesced run ----
    uint2 ga[4][4];
    #pragma unroll
    for (int i = 0; i < 4; ++i) {
        const int jl = i * 2 + s2;             // 0..7
        int4 o;
        o.x = __shfl(o4x, jl); o.y = __shfl(o4y, jl);
        o.z = __shfl(o4z, jl); o.w = __shfl(o4w, jl);
        ga[i][0] = *(const uint2*)(fb + (size_t)o.x * C2D);
        ga[i][1] = *(const uint2*)(fb + (size_t)o.y * C2D);
        ga[i][2] = *(const uint2*)(fb + (size_t)o.z * C2D);
        ga[i][3] = *(const uint2*)(fb + (size_t)o.w * C2D);
    }

    // ---- f3d -> cat[n][128+c] (covers batch-A flight). lane = sample,
    // wave wv covers 32 channels; coalesced 4B loads, b128 LDS writes. ----
    {
        const float* p3 = f3d + (size_t)(b * C3D) * NSAMP + n0 + lane;
        #pragma unroll
        for (int ch = 0; ch < 4; ++ch) {
            const int cbase = wv * 32 + ch * 8;
            float v[8];
            #pragma unroll
            for (int t = 0; t < 8; ++t) v[t] = p3[(size_t)(cbase + t) * NSAMP];
            uint4 pk;
            pk.x = pack2(v[0], v[1]);
            pk.y = pack2(v[2], v[3]);
            pk.z = pack2(v[4], v[5]);
            pk.w = pack2(v[6], v[7]);
            *(uint4*)&catw[lane * (CATS / 2) + (C2D / 2) + (cbase >> 1)] = pk;
        }
    }

    // ---- issue gather batch B: samples wv*16 + 8 + i*2+s2 ----
    uint2 gb[4][4];
    #pragma unroll
    for (int i = 0; i < 4; ++i) {
        const int jl = 8 + i * 2 + s2;         // 8..15
        int4 o;
        o.x = __shfl(o4x, jl); o.y = __shfl(o4y, jl);
        o.z = __shfl(o4z, jl); o.w = __shfl(o4w, jl);
        gb[i][0] = *(const uint2*)(fb + (size_t)o.x * C2D);
        gb[i][1] = *(const uint2*)(fb + (size_t)o.y * C2D);
        gb[i][2] = *(const uint2*)(fb + (size_t)o.z * C2D);
        gb[i][3] = *(const uint2*)(fb + (size_t)o.w * C2D);
    }

    // ---- blend A (VALU, covers batch-B flight), then blend B ----
    #pragma unroll
    for (int i = 0; i < 4; ++i) {
        const int jl = i * 2 + s2;
        float4 bw;
        bw.x = __shfl(w4x, jl); bw.y = __shfl(w4y, jl);
        bw.z = __shfl(w4z, jl); bw.w = __shfl(w4w, jl);
        blend_write(ga[i], bw, catw, wv * 16 + jl, ch4);
    }
    #pragma unroll
    for (int i = 0; i < 4; ++i) {
        const int jl = 8 + i * 2 + s2;
        float4 bw;
        bw.x = __shfl(w4x, jl); bw.y = __shfl(w4y, jl);
        bw.z = __shfl(w4z, jl); bw.w = __shfl(w4w, jl);
        blend_write(gb[i], bw, catw, wv * 16 + jl, ch4);
    }
    __syncthreads();   // the ONLY barrier: full cat tile ready

    // ---- GEMM: D[128 x 64] = Wb[128 x 256] @ cat^T, 32 unbroken MFMA.
    // A-frags loaded by pointer arithmetic (runtime ADDRESS ok; runtime
    // array INDEX would spill - rule #20 / round-9). ----
    const int quad = lane >> 4;
    const int nloc = lane & 15;

    f32x4 acc[2][4];
    #pragma unroll
    for (int mt = 0; mt < 2; ++mt)
        #pragma unroll
        for (int nt = 0; nt < 4; ++nt)
            acc[mt][nt] = (f32x4){0.f, 0.f, 0.f, 0.f};

    const unsigned short* wb0 = Wb + (size_t)(wv * 32 + nloc) * KK + quad * 8;

    __builtin_amdgcn_s_setprio(1);   // T5: prefer MFMA-phase waves
    #pragma unroll 2
    for (int ks = 0; ks < 8; ++ks) {
        const int k0 = ks * 32;
        const bf16x8 a0 = *(const bf16x8*)(wb0 + k0);
        const bf16x8 a1 = *(const bf16x8*)(wb0 + 16 * KK + k0);
        #pragma unroll
        for (int nt = 0; nt < 4; ++nt) {
            const bf16x8 bfrag = *(const bf16x8*)
                &cat[(nt * 16 + nloc) * CATS + k0 + quad * 8];
            acc[0][nt] = __builtin_amdgcn_mfma_f32_16x16x32_bf16(
                a0, bfrag, acc[0][nt], 0, 0, 0);
            acc[1][nt] = __builtin_amdgcn_mfma_f32_16x16x32_bf16(
                a1, bfrag, acc[1][nt], 0, 0, 0);
        }
    }
    __builtin_amdgcn_s_setprio(0);

    // ---- Epilogue: bias + leaky-relu; C/D layout col=lane&15, row=quad*4+r ----
    #pragma unroll
    for (int mt = 0; mt < 2; ++mt) {
        const int cobase = wv * 32 + mt * 16 + quad * 4;
        float bv[4];
        #pragma unroll
        for (int r = 0; r < 4; ++r) bv[r] = bias[cobase + r];
        #pragma unroll
        for (int nt = 0; nt < 4; ++nt) {
            float* po = out + (size_t)(b * COUT + cobase) * NSAMP
                      + n0 + nt * 16 + nloc;
            #pragma unroll
            for (int r = 0; r < 4; ++r) {
                float yv = acc[mt][nt][r] + bv[r];
                yv = (yv >= 0.0f) ? yv : 0.1f * yv;
                po[(size_t)r * NSAMP] = yv;
            }
        }
    }
}

extern "C" void kernel_launch(void* const* d_in, const int* in_sizes, int n_in,
                              void* d_out, int out_size, void* d_ws, size_t ws_size,
                              hipStream_t stream) {
    const float* xy   = (const float*)d_in[0];
    const float* f2d  = (const float*)d_in[1];
    const float* f3d  = (const float*)d_in[2];
    const float* Wm   = (const float*)d_in[3];
    const float* bias = (const float*)d_in[4];
    float* out = (float*)d_out;

    // ws layout: f2dt bf16 [B*HW*C2D] (15.73 MB), then Wb bf16 [COUT*KK]
    unsigned short* f2dt = (unsigned short*)d_ws;
    unsigned short* Wb   = f2dt + (size_t)BB * HW * C2D;

    // 480 transpose blocks + 16 wcvt blocks in one launch
    transpose_cvt_kernel<<<dim3(496), 512, 0, stream>>>(f2d, f2dt, Wm, Wb);
    fuse_kernel<<<dim3(BB * (NSAMP / TN)), 256, 0, stream>>>(
        xy, f2dt, f3d, Wb, bias, out);
}